// Round 1
// baseline (10301.665 us; speedup 1.0000x reference)
//
#include <hip/hip_runtime.h>
#include <hip/hip_bf16.h>

// SRPBlock forward: x=concat(old,new) [4,64,256,256]
//   q=conv(x,wq,bq); k=conv(x,wk,bk); att=local_similar(q,k) [4,81,256,256]
//   v=conv(att,wv,bv); y=conv(x*v,wo1,bo1); 8x ResBlock; y=conv(y,wo2,bo2); out=y+x
// All fp32. Direct tiled conv: block=16x16 pixels, 16 out-ch per thread.

#define H 256
#define W 256
#define PLANE (H * W)

// -------- conv3x3 pad=1, Cout=64 --------
// grid: (W/16, H/16, B*4); block: 256
// LDS tile: 18 rows x 18 cols, stride 48 (rows land on banks {0,16} mod 32 -> free 2-way)
template <bool BIAS, bool LEAKY, bool ADDSRC>
__global__ __launch_bounds__(256) void conv3x3(
    const float* __restrict__ in0, const float* __restrict__ in1, int c_split,
    int Cin, const float* __restrict__ w, const float* __restrict__ bias,
    const float* __restrict__ addsrc, float* __restrict__ out)
{
    __shared__ float tile[18 * 48];

    const int tid = threadIdx.x;
    const int tx = tid & 15, ty = tid >> 4;
    const int bx = blockIdx.x * 16, by = blockIdx.y * 16;
    const int og = blockIdx.z & 3;        // out-channel group of 16
    const int b  = blockIdx.z >> 2;

    // staging assignment (324 halo elems over 256 threads, <=2 each)
    const int s0 = tid, s1 = tid + 256;
    const int r0 = s0 / 18, q0 = s0 % 18;
    const int r1 = s1 / 18, q1 = s1 % 18;
    const int a0 = r0 * 48 + q0, a1 = r1 * 48 + q1;
    const int gy0 = by + r0 - 1, gx0 = bx + q0 - 1;
    const int gy1 = by + r1 - 1, gx1 = bx + q1 - 1;
    const bool v0 = (gy0 >= 0) & (gy0 < H) & (gx0 >= 0) & (gx0 < W);
    const bool v1 = (s1 < 324) & (gy1 >= 0) & (gy1 < H) & (gx1 >= 0) & (gx1 < W);
    const int off0 = gy0 * W + gx0;
    const int off1 = gy1 * W + gx1;

    float acc[16];
#pragma unroll
    for (int o = 0; o < 16; ++o) acc[o] = 0.f;

    for (int c = 0; c < Cin; ++c) {
        const float* inp = (c < c_split)
            ? in0 + ((size_t)b * c_split + c) * PLANE
            : in1 + ((size_t)b * (Cin - c_split) + (c - c_split)) * PLANE;

        __syncthreads();
        tile[a0] = v0 ? inp[off0] : 0.f;
        if (s1 < 324) tile[a1] = v1 ? inp[off1] : 0.f;
        __syncthreads();

        float in9[9];
#pragma unroll
        for (int dy = 0; dy < 3; ++dy)
#pragma unroll
            for (int dx = 0; dx < 3; ++dx)
                in9[dy * 3 + dx] = tile[(ty + dy) * 48 + (tx + dx)];

        const float* wc = w + ((size_t)(og * 16) * Cin + c) * 9;
#pragma unroll
        for (int o = 0; o < 16; ++o) {
            const float* wo = wc + (size_t)o * Cin * 9;
#pragma unroll
            for (int k = 0; k < 9; ++k)
                acc[o] = fmaf(in9[k], wo[k], acc[o]);
        }
    }

    const size_t obase = ((size_t)b * 64 + og * 16) * PLANE + (size_t)(by + ty) * W + (bx + tx);
#pragma unroll
    for (int o = 0; o < 16; ++o) {
        float r = acc[o];
        if (BIAS)  r += bias[og * 16 + o];
        if (LEAKY) r = (r >= 0.f) ? r : 0.2f * r;
        if (ADDSRC) r += addsrc[obase + (size_t)o * PLANE];
        out[obase + (size_t)o * PLANE] = r;
    }
}

// -------- local similarity: att[b, di*9+dj, y, x] = sum_c q[b,c,y,x]*k[b,c,y+di-4,x+dj-4]
// grid: (81, H, B); block: 256 (one row of x)
__global__ __launch_bounds__(256) void local_sim(
    const float* __restrict__ q, const float* __restrict__ k, float* __restrict__ att)
{
    const int x = threadIdx.x;
    const int p = blockIdx.x;    // 0..80
    const int y = blockIdx.y;
    const int b = blockIdx.z;
    const int di = p / 9, dj = p % 9;
    const int ky = y + di - 4;
    const int kx = x + dj - 4;

    float s = 0.f;
    if (ky >= 0 && ky < H) {                     // block-uniform branch
        const bool valid = (kx >= 0) & (kx < W);
        const float* qp = q + (size_t)b * 64 * PLANE + (size_t)y * W + x;
        const float* kp = k + (size_t)b * 64 * PLANE + (size_t)ky * W + (valid ? kx : 0);
        float acc = 0.f;
#pragma unroll 8
        for (int c = 0; c < 64; ++c)
            acc = fmaf(qp[(size_t)c * PLANE], kp[(size_t)c * PLANE], acc);
        s = valid ? acc : 0.f;
    }
    att[((size_t)b * 81 + p) * PLANE + (size_t)y * W + x] = s;
}

// -------- xv = concat(old,new) * v --------
__global__ __launch_bounds__(256) void mul_xcat(
    const float* __restrict__ old_, const float* __restrict__ new_,
    const float* __restrict__ v, float* __restrict__ xv)
{
    const int i = blockIdx.x * 256 + threadIdx.x;    // < 4*64*65536
    const int pix = i & 65535;
    const int c = (i >> 16) & 63;
    const int b = i >> 22;
    const float xval = (c < 32)
        ? old_[(((size_t)b * 32 + c) << 16) | pix]
        : new_[(((size_t)b * 32 + (c - 32)) << 16) | pix];
    xv[i] = xval * v[i];
}

// -------- out += concat(old,new) --------
__global__ __launch_bounds__(256) void add_xcat(
    const float* __restrict__ old_, const float* __restrict__ new_, float* __restrict__ out)
{
    const int i = blockIdx.x * 256 + threadIdx.x;
    const int pix = i & 65535;
    const int c = (i >> 16) & 63;
    const int b = i >> 22;
    const float xval = (c < 32)
        ? old_[(((size_t)b * 32 + c) << 16) | pix]
        : new_[(((size_t)b * 32 + (c - 32)) << 16) | pix];
    out[i] += xval;
}

extern "C" void kernel_launch(void* const* d_in, const int* in_sizes, int n_in,
                              void* d_out, int out_size, void* d_ws, size_t ws_size,
                              hipStream_t stream)
{
    const float* old_ = (const float*)d_in[0];
    const float* new_ = (const float*)d_in[1];
    const float* wq  = (const float*)d_in[2];  const float* bq  = (const float*)d_in[3];
    const float* wk  = (const float*)d_in[4];  const float* bk  = (const float*)d_in[5];
    const float* wv  = (const float*)d_in[6];  const float* bv  = (const float*)d_in[7];
    const float* wo1 = (const float*)d_in[8];  const float* bo1 = (const float*)d_in[9];
    const float* rw1 = (const float*)d_in[10]; const float* rw2 = (const float*)d_in[11];
    const float* wo2 = (const float*)d_in[12]; const float* bo2 = (const float*)d_in[13];
    float* out = (float*)d_out;

    char* ws = (char*)d_ws;
    const size_t buf64 = (size_t)4 * 64 * PLANE * sizeof(float);   // 64 MiB
    float* q   = (float*)(ws);
    float* kk  = (float*)(ws + buf64);
    float* att = (float*)(ws + 2 * buf64);   // 81 MiB region
    float* v   = q;     // reuse: q dead after att
    float* xv  = kk;    // reuse: k dead after att
    float* y   = att;   // reuse: att dead after v (64 MiB <= 81 MiB)
    float* h1  = q;     // reuse: v dead after xv

    const dim3 cgrid(16, 16, 16), cblk(256);
    const dim3 egrid(65536), eblk(256);

    // q, k
    conv3x3<true, false, false><<<cgrid, cblk, 0, stream>>>(old_, new_, 32, 64, wq, bq, nullptr, q);
    conv3x3<true, false, false><<<cgrid, cblk, 0, stream>>>(old_, new_, 32, 64, wk, bk, nullptr, kk);
    // att
    local_sim<<<dim3(81, 256, 4), 256, 0, stream>>>(q, kk, att);
    // v = conv(att)
    conv3x3<true, false, false><<<cgrid, cblk, 0, stream>>>(att, att, 81, 81, wv, bv, nullptr, v);
    // xv = x * v
    mul_xcat<<<egrid, eblk, 0, stream>>>(old_, new_, v, xv);
    // y = conv(xv, wo1, bo1)
    conv3x3<true, false, false><<<cgrid, cblk, 0, stream>>>(xv, xv, 64, 64, wo1, bo1, nullptr, y);
    // 8 ResBlocks
    for (int i = 0; i < 8; ++i) {
        const float* w1 = rw1 + (size_t)i * 64 * 64 * 9;
        const float* w2 = rw2 + (size_t)i * 64 * 64 * 9;
        conv3x3<false, true,  false><<<cgrid, cblk, 0, stream>>>(y,  y,  64, 64, w1, nullptr, nullptr, h1);
        conv3x3<false, false, true ><<<cgrid, cblk, 0, stream>>>(h1, h1, 64, 64, w2, nullptr, y, y);
    }
    // final conv + skip
    conv3x3<true, false, false><<<cgrid, cblk, 0, stream>>>(y, y, 64, 64, wo2, bo2, nullptr, out);
    add_xcat<<<egrid, eblk, 0, stream>>>(old_, new_, out);
}

// Round 2
// 1643.799 us; speedup vs baseline: 6.2670x; 6.2670x over previous
//
#include <hip/hip_runtime.h>
#include <hip/hip_bf16.h>

// SRPBlock forward, MFMA bf16 implicit-GEMM convs.
// x=concat(old,new) [4,64,256,256] fp32 NCHW (inputs), activations flow as
// bf16 [b][pix][ch] (channel-contiguous) for MFMA; y-residual master in fp32.

#define HH 256
#define WW 256
#define PLANE 65536

typedef __bf16 bf16x8 __attribute__((ext_vector_type(8)));
typedef float  f32x4  __attribute__((ext_vector_type(4)));

__device__ __forceinline__ unsigned short f2bf(float f) {
    unsigned int u = __builtin_bit_cast(unsigned int, f);
    u += 0x7fffu + ((u >> 16) & 1u);          // RNE (finite values only)
    return (unsigned short)(u >> 16);
}

__device__ __forceinline__ float pairdot(unsigned a, unsigned b) {
    float a0 = __builtin_bit_cast(float, a << 16);
    float a1 = __builtin_bit_cast(float, a & 0xffff0000u);
    float b0 = __builtin_bit_cast(float, b << 16);
    float b1 = __builtin_bit_cast(float, b & 0xffff0000u);
    return fmaf(a0, b0, a1 * b1);
}

// ---------------- conv3x3 (pad=1, Cout=64) via MFMA 16x16x32 bf16 ----------------
// block = 256 thr = 4 waves; tile = 16x16 pixels x 64 outch.
// Wave w: all 64 outch x 64 pixels (rows 4w..4w+3). 16 MFMAs per 32-K-chunk from
// 4 A + 4 B ds_read_b128 (XOR-swizzled, conflict-free).
// K = 9 taps x CIN channels, channel-chunked by CH (LDS <= 64 KB).
template <int CIN, int CH, bool BIAS, bool LEAKY, bool ADDF, bool ADDX, bool MULX,
          bool OUTF, bool OUTB>
__global__ __launch_bounds__(256, 2) void conv_mfma(
    const unsigned short* __restrict__ in_pc,  // [b][65536][CIN] bf16
    const unsigned short* __restrict__ wb,     // [9][64][CIN] bf16
    const float* __restrict__ bias,
    const float* __restrict__ addf,            // fp32 NCHW addend (residual)
    const float* __restrict__ xold,            // fp32 NCHW [4,32,...]
    const float* __restrict__ xnew,
    float* __restrict__ outf,                  // fp32 NCHW
    unsigned short* __restrict__ outb)         // [b][65536][64] bf16
{
    constexpr int NCH   = CIN / CH;
    constexpr int PARTS = CH / 8;        // 16B units per pixel-row chunk
    constexpr int SWZ   = PARTS - 1;     // XOR swizzle mask
    constexpr int KC    = CH / 32;
    constexpr int INSZ  = (324 * CH > 256 * 64) ? 324 * CH : 256 * 64;

    __shared__ unsigned short lds_in[INSZ];
    __shared__ unsigned short lds_w[2][64 * CH];

    const int tid = threadIdx.x;
    const int w   = tid >> 6;
    const int ln  = tid & 63;
    const int m   = ln & 15;    // outch-in-group for A; pixel-col for B/D
    const int q   = ln >> 4;    // quad
    const int b   = blockIdx.z;
    const int tx0 = blockIdx.x * 16, ty0 = blockIdx.y * 16;
    const size_t pixb = (size_t)b * PLANE;

    f32x4 acc[4][4];
#pragma unroll
    for (int g = 0; g < 4; ++g)
#pragma unroll
        for (int p = 0; p < 4; ++p) acc[g][p] = (f32x4)0.f;

    for (int c2 = 0; c2 < NCH; ++c2) {
        // ---- stage halo chunk: 324 px x CH ch ----
        for (int u = tid; u < 324 * PARTS; u += 256) {
            int pix  = u / PARTS;
            int part = u - pix * PARTS;
            int hy = pix / 18, hx = pix - hy * 18;
            int gy = ty0 + hy - 1, gx = tx0 + hx - 1;
            uint4 val = make_uint4(0u, 0u, 0u, 0u);
            if ((unsigned)gy < 256u && (unsigned)gx < 256u)
                val = *reinterpret_cast<const uint4*>(
                    in_pc + ((pixb + (size_t)gy * 256 + gx) * CIN + c2 * CH + part * 8));
            int pp = part ^ (pix & SWZ);
            *reinterpret_cast<uint4*>(&lds_in[pix * CH + pp * 8]) = val;
        }
        // ---- stage weights tap 0 ----
        {
            for (int u = tid; u < 64 * PARTS; u += 256) {
                int oc = u / PARTS, part = u - oc * PARTS;
                uint4 val = *reinterpret_cast<const uint4*>(
                    wb + ((size_t)(0 * 64 + oc) * CIN + c2 * CH + part * 8));
                int pp = part ^ (oc & SWZ);
                *reinterpret_cast<uint4*>(&lds_w[0][oc * CH + pp * 8]) = val;
            }
        }
        __syncthreads();

        for (int t = 0; t < 9; ++t) {
            if (t < 8) {  // prefetch next tap's weights into other buffer
                int bsel = (t + 1) & 1;
                for (int u = tid; u < 64 * PARTS; u += 256) {
                    int oc = u / PARTS, part = u - oc * PARTS;
                    uint4 val = *reinterpret_cast<const uint4*>(
                        wb + ((size_t)((t + 1) * 64 + oc) * CIN + c2 * CH + part * 8));
                    int pp = part ^ (oc & SWZ);
                    *reinterpret_cast<uint4*>(&lds_w[bsel][oc * CH + pp * 8]) = val;
                }
            }
            const int dy = t / 3, dx = t - dy * 3;
            const unsigned short* wl = lds_w[t & 1];
#pragma unroll
            for (int kc = 0; kc < KC; ++kc) {
                bf16x8 av[4], bv[4];
#pragma unroll
                for (int g = 0; g < 4; ++g) {
                    int oc = g * 16 + m;
                    int pp = (kc * 4 + q) ^ (oc & SWZ);
                    av[g] = *reinterpret_cast<const bf16x8*>(&wl[oc * CH + pp * 8]);
                }
#pragma unroll
                for (int p = 0; p < 4; ++p) {
                    int hp = (w * 4 + p + dy) * 18 + m + dx;
                    int pp = (kc * 4 + q) ^ (hp & SWZ);
                    bv[p] = *reinterpret_cast<const bf16x8*>(&lds_in[hp * CH + pp * 8]);
                }
#pragma unroll
                for (int g = 0; g < 4; ++g)
#pragma unroll
                    for (int p = 0; p < 4; ++p)
                        acc[g][p] = __builtin_amdgcn_mfma_f32_16x16x32_bf16(
                            av[g], bv[p], acc[g][p], 0, 0, 0);
            }
            __syncthreads();
        }
    }

    // ---------------- epilogue ----------------
    // D layout: row(outch-in-grp) = q*4+reg, col(pixel) = m
    const int colx = tx0 + m;
    float4 bvec[4];
    if (BIAS) {
#pragma unroll
        for (int g = 0; g < 4; ++g)
            bvec[g] = *reinterpret_cast<const float4*>(bias + g * 16 + q * 4);
    }

#pragma unroll
    for (int g = 0; g < 4; ++g) {
#pragma unroll
        for (int p = 0; p < 4; ++p) {
            const int prow = w * 4 + p;
            const int gy   = ty0 + prow;
            float vals[4];
#pragma unroll
            for (int r = 0; r < 4; ++r) {
                int oc = g * 16 + q * 4 + r;
                float v = acc[g][p][r];
                if (BIAS) v += reinterpret_cast<const float*>(&bvec[g])[r];
                if (LEAKY) v = (v >= 0.f) ? v : 0.2f * v;
                size_t nchw = ((size_t)(b * 64 + oc)) * PLANE + (size_t)gy * 256 + colx;
                if (ADDF) v += addf[nchw];
                if (ADDX) {
                    const float* xp = (g < 2) ? xold : xnew;
                    v += xp[((size_t)(b * 32 + (oc & 31))) * PLANE + (size_t)gy * 256 + colx];
                }
                if (MULX) {
                    const float* xp = (g < 2) ? xold : xnew;
                    v *= xp[((size_t)(b * 32 + (oc & 31))) * PLANE + (size_t)gy * 256 + colx];
                }
                if (OUTF) outf[nchw] = v;
                vals[r] = v;
            }
            if (OUTB) {  // stage to LDS for [pix][ch] vector store
                ushort4 pk;
                pk.x = f2bf(vals[0]); pk.y = f2bf(vals[1]);
                pk.z = f2bf(vals[2]); pk.w = f2bf(vals[3]);
                int pix   = prow * 16 + m;
                int part8 = g * 4 + q;
                int p16   = (part8 >> 1) ^ (pix & 7);
                *reinterpret_cast<ushort4*>(&lds_in[pix * 64 + p16 * 8 + (part8 & 1) * 4]) = pk;
            }
        }
    }
    if (OUTB) {
        __syncthreads();
        for (int u = tid; u < 2048; u += 256) {
            int pix = u >> 3, p16 = u & 7;
            uint4 val = *reinterpret_cast<const uint4*>(
                &lds_in[pix * 64 + ((p16 ^ (pix & 7)) * 8)]);
            int gy = ty0 + (pix >> 4), gx = tx0 + (pix & 15);
            *reinterpret_cast<uint4*>(
                &outb[(pixb + (size_t)gy * 256 + gx) * 64 + p16 * 8]) = val;
        }
    }
}

// ---------------- local similarity ----------------
// att[b][pix][p] = dot64(q[pix], k[pix + (di-4,dj-4)]), p = di*9+dj; ch 81..95 = 0.
// One thread per pixel; q/k bf16 [pix][64]; out bf16 [pix][96].
__global__ __launch_bounds__(256) void local_sim(
    const unsigned short* __restrict__ qb, const unsigned short* __restrict__ kb,
    unsigned short* __restrict__ att)
{
    const int x = threadIdx.x;
    const int y = blockIdx.x;
    const int b = blockIdx.y;
    const size_t pixb = (size_t)b * PLANE;
    const unsigned short* qp = qb + (pixb + (size_t)y * 256 + x) * 64;
    uint4 qv[8];
#pragma unroll
    for (int j = 0; j < 8; ++j)
        qv[j] = *reinterpret_cast<const uint4*>(qp + j * 8);

    unsigned short* op = att + (pixb + (size_t)y * 256 + x) * 96;
    float buf[8];

#pragma unroll
    for (int di = 0; di < 9; ++di) {
        const int ky = y + di - 4;
        const bool rv = ((unsigned)ky < 256u);
#pragma unroll
        for (int dj = 0; dj < 9; ++dj) {
            const int p = di * 9 + dj;
            float s = 0.f;
            if (rv) {
                int kx = x + dj - 4;
                bool cv = ((unsigned)kx < 256u);
                int kxc = cv ? kx : 0;
                const unsigned short* kp = kb + (pixb + (size_t)ky * 256 + kxc) * 64;
                float a = 0.f;
#pragma unroll
                for (int j = 0; j < 8; ++j) {
                    uint4 kv = *reinterpret_cast<const uint4*>(kp + j * 8);
                    a += pairdot(qv[j].x, kv.x) + pairdot(qv[j].y, kv.y) +
                         pairdot(qv[j].z, kv.z) + pairdot(qv[j].w, kv.w);
                }
                s = cv ? a : 0.f;
            }
            buf[p & 7] = s;
            if ((p & 7) == 7) {
                uint4 o;
                o.x = f2bf(buf[0]) | ((unsigned)f2bf(buf[1]) << 16);
                o.y = f2bf(buf[2]) | ((unsigned)f2bf(buf[3]) << 16);
                o.z = f2bf(buf[4]) | ((unsigned)f2bf(buf[5]) << 16);
                o.w = f2bf(buf[6]) | ((unsigned)f2bf(buf[7]) << 16);
                *reinterpret_cast<uint4*>(op + (p >> 3) * 8) = o;
            }
        }
    }
    // tail: p=80 in buf[0]; channels 81..95 zero
    {
        uint4 o;
        o.x = f2bf(buf[0]);
        o.y = 0u; o.z = 0u; o.w = 0u;
        *reinterpret_cast<uint4*>(op + 80) = o;
        uint4 z = make_uint4(0u, 0u, 0u, 0u);
        *reinterpret_cast<uint4*>(op + 88) = z;
    }
}

// ---------------- pack x: fp32 NCHW old/new -> bf16 [b][pix][64] ----------------
__global__ __launch_bounds__(256) void pack_x(
    const float* __restrict__ old_, const float* __restrict__ new_,
    unsigned short* __restrict__ xb)
{
    __shared__ unsigned short lds[256 * 64];
    const int tid = threadIdx.x;
    const int b = blockIdx.y;
    const size_t pixbase = (size_t)blockIdx.x * 256;
#pragma unroll
    for (int cg = 0; cg < 8; ++cg) {
        unsigned pk[4];
#pragma unroll
        for (int h = 0; h < 4; ++h) {
            int c0 = cg * 8 + h * 2;
            const float* s0 = (c0 < 32) ? old_ : new_;
            const float* s1 = ((c0 + 1) < 32) ? old_ : new_;
            float f0 = s0[((size_t)b * 32 + (c0 & 31)) * PLANE + pixbase + tid];
            float f1 = s1[((size_t)b * 32 + ((c0 + 1) & 31)) * PLANE + pixbase + tid];
            pk[h] = f2bf(f0) | ((unsigned)f2bf(f1) << 16);
        }
        int p16 = cg ^ (tid & 7);
        uint4 v; v.x = pk[0]; v.y = pk[1]; v.z = pk[2]; v.w = pk[3];
        *reinterpret_cast<uint4*>(&lds[tid * 64 + p16 * 8]) = v;
    }
    __syncthreads();
    for (int r = 0; r < 8; ++r) {
        int u = r * 256 + tid;
        int pix = u >> 3, p16 = u & 7;
        uint4 v = *reinterpret_cast<const uint4*>(&lds[pix * 64 + ((p16 ^ (pix & 7)) * 8)]);
        *reinterpret_cast<uint4*>(
            &xb[((size_t)b * PLANE + pixbase + pix) * 64 + p16 * 8]) = v;
    }
}

// ---------------- weight prep: fp32 OIHW -> bf16 [9][64][CIN] ----------------
__global__ void prep_wstd(const float* __restrict__ wq, const float* __restrict__ wk,
                          const float* __restrict__ wo1, const float* __restrict__ wo2,
                          const float* __restrict__ rw1, const float* __restrict__ rw2,
                          unsigned short* __restrict__ wstd)
{
    const int c = blockIdx.y;  // 0..19
    const float* src;
    if (c == 0) src = wq;
    else if (c == 1) src = wk;
    else if (c == 2) src = wo1;
    else if (c == 3) src = wo2;
    else if (c < 12) src = rw1 + (size_t)(c - 4) * 36864;
    else src = rw2 + (size_t)(c - 12) * 36864;
    int idx = blockIdx.x * 256 + threadIdx.x;  // 0..4095
    int o = idx >> 6, i = idx & 63;
    const float* s = src + (size_t)(o * 64 + i) * 9;
    unsigned short* d = wstd + (size_t)c * 36864 + (size_t)o * 64 + i;
#pragma unroll
    for (int t = 0; t < 9; ++t) d[(size_t)t * 4096] = f2bf(s[t]);
}

__global__ void prep_wv(const float* __restrict__ wv, unsigned short* __restrict__ wv96)
{
    int idx = blockIdx.x * 256 + threadIdx.x;  // < 6144
    int o = idx / 96, i = idx - o * 96;
    unsigned short* d = wv96 + (size_t)o * 96 + i;
    if (i < 81) {
        const float* s = wv + (size_t)(o * 81 + i) * 9;
#pragma unroll
        for (int t = 0; t < 9; ++t) d[(size_t)t * 6144] = f2bf(s[t]);
    } else {
#pragma unroll
        for (int t = 0; t < 9; ++t) d[(size_t)t * 6144] = 0;
    }
}

extern "C" void kernel_launch(void* const* d_in, const int* in_sizes, int n_in,
                              void* d_out, int out_size, void* d_ws, size_t ws_size,
                              hipStream_t stream)
{
    const float* old_ = (const float*)d_in[0];
    const float* new_ = (const float*)d_in[1];
    const float* wq  = (const float*)d_in[2];  const float* bq  = (const float*)d_in[3];
    const float* wk  = (const float*)d_in[4];  const float* bk  = (const float*)d_in[5];
    const float* wv  = (const float*)d_in[6];  const float* bv  = (const float*)d_in[7];
    const float* wo1 = (const float*)d_in[8];  const float* bo1 = (const float*)d_in[9];
    const float* rw1 = (const float*)d_in[10]; const float* rw2 = (const float*)d_in[11];
    const float* wo2 = (const float*)d_in[12]; const float* bo2 = (const float*)d_in[13];
    float* out = (float*)d_out;

    char* ws = (char*)d_ws;
    // B: qb -> xvb -> h1b (32 MiB)
    // C: kb -> yb_a       (32 MiB)
    // D: xb(32) -> att96(48) -> yb_b(32)
    // yf: fp32 y master (64 MiB); then bf16 weights
    unsigned short* B   = (unsigned short*)(ws);
    unsigned short* C   = (unsigned short*)(ws + 33554432ull);
    unsigned short* D   = (unsigned short*)(ws + 67108864ull);
    float*          yf  = (float*)(ws + 117440512ull);
    unsigned short* wst = (unsigned short*)(ws + 184549376ull);   // 20*36864 bf16
    unsigned short* wv96= (unsigned short*)(ws + 186023936ull);   // 9*64*96 bf16

    const dim3 cgrid(16, 16, 4), cblk(256);

    prep_wstd<<<dim3(16, 20), 256, 0, stream>>>(wq, wk, wo1, wo2, rw1, rw2, wst);
    prep_wv<<<dim3(24), 256, 0, stream>>>(wv, wv96);
    pack_x<<<dim3(256, 4), 256, 0, stream>>>(old_, new_, D);

    // q = conv(x, wq, bq); k = conv(x, wk, bk)
    conv_mfma<64, 64, true, false, false, false, false, false, true>
        <<<cgrid, cblk, 0, stream>>>(D, wst + 0ull * 36864, bq, nullptr, nullptr, nullptr, nullptr, B);
    conv_mfma<64, 64, true, false, false, false, false, false, true>
        <<<cgrid, cblk, 0, stream>>>(D, wst + 1ull * 36864, bk, nullptr, nullptr, nullptr, nullptr, C);
    // att
    local_sim<<<dim3(256, 4), 256, 0, stream>>>(B, C, D);
    // xv = x * (conv(att, wv) + bv)   [MULX fused]
    conv_mfma<96, 32, true, false, false, false, true, false, true>
        <<<cgrid, cblk, 0, stream>>>(D, wv96, bv, nullptr, old_, new_, nullptr, B);
    // y = conv(xv, wo1, bo1) -> yf (fp32) + yb (C)
    conv_mfma<64, 64, true, false, false, false, false, true, true>
        <<<cgrid, cblk, 0, stream>>>(B, wst + 2ull * 36864, bo1, nullptr, nullptr, nullptr, yf, C);
    // 8 ResBlocks, yb ping-pong C <-> D, h1 in B
    for (int i = 0; i < 8; ++i) {
        unsigned short* src = (i & 1) ? D : C;
        unsigned short* dst = (i & 1) ? C : D;
        conv_mfma<64, 64, false, true, false, false, false, false, true>
            <<<cgrid, cblk, 0, stream>>>(src, wst + (size_t)(4 + i) * 36864, nullptr,
                                         nullptr, nullptr, nullptr, nullptr, B);
        conv_mfma<64, 64, false, false, true, false, false, true, true>
            <<<cgrid, cblk, 0, stream>>>(B, wst + (size_t)(12 + i) * 36864, nullptr,
                                         yf, nullptr, nullptr, yf, dst);
    }
    // out = conv(y, wo2, bo2) + x   [ADDX fused]; final yb is in C
    conv_mfma<64, 64, true, false, false, true, false, true, false>
        <<<cgrid, cblk, 0, stream>>>(C, wst + 3ull * 36864, bo2, nullptr, old_, new_, out, nullptr);
}